// Round 4
// baseline (190.573 us; speedup 1.0000x reference)
//
#include <hip/hip_runtime.h>

// 10-qubit circuit sim: RY(theta_i) per wire + CNOT chain, then <X,Y,Z> per wire,
// on 32768 L2-normalized real states of dim 1024.
//
// Math:
//  * state stays REAL -> Y_i == 0 exactly.
//  * CNOT chain == Gray map: final[x] = pre[x ^ (x>>1)]; folded into measurement:
//      X_w: pair-corr at delta_b = 3<<(b-1) (delta_0=1), b = 9-w
//      Z_w: parity-signed sum of squares, parity over amp bits b..9
//  * normalization deferred (divide by n2 = sum v^2 at the end; RY is orthogonal
//    so n2 == initial norm^2 and is read off the final state).
//
// Layout: wave64 = 2 states (lanes 0-31 / 32-63); each lane holds 32 amps in VGPRs.
// Amp bit k <-> wire 9-k.  Phase plan (reg-resident amp bits):
//   L0 = [0,1,7,8,9]  (coalesced load; gates w9,w8,w2,w1,w0)
//   RT1 -> L1 = [2,3,4,5,6] (gates w7..w3; ALL Z; X edges 23,34,45,56;
//                            X edges 01,12 via quad_perm DPP cross-lane)
//   RT2 -> L3 = [0,6,7,8,9] (X edges (0),67,78,89 — all register-local)
// Only 2 LDS round-trips (wave-private slabs, no __syncthreads), bank-exact
// swizzles derived per-RT, +4-float state stagger to split half-wave bank sets.

#define NQ 10
#define DIM 1024
#define SLABF 1028  // floats per state (1024 + 4 stagger)

template <int CTRL, int RMASK>
__device__ __forceinline__ float dpp_mov(float x) {
    return __int_as_float(
        __builtin_amdgcn_update_dpp(0, __float_as_int(x), CTRL, RMASK, 0xF, true));
}

// 32-lane sum; result lands in lanes 31 and 63. Pure VALU.
__device__ __forceinline__ float red32(float x) {
    x += dpp_mov<0x111, 0xF>(x);  // row_shr:1
    x += dpp_mov<0x112, 0xF>(x);  // row_shr:2
    x += dpp_mov<0x114, 0xF>(x);  // row_shr:4
    x += dpp_mov<0x118, 0xF>(x);  // row_shr:8
    x += dpp_mov<0x142, 0xA>(x);  // row_bcast:15 into rows 1,3
    return x;
}

template <int MASK>
__device__ __forceinline__ void gate(float (&v)[32], float cc, float ss) {
#pragma unroll
    for (int j = 0; j < 32; ++j) {
        if ((j & MASK) == 0) {
            const float a0 = v[j], a1 = v[j | MASK];
            v[j]        = cc * a0 - ss * a1;
            v[j | MASK] = ss * a0 + cc * a1;
        }
    }
}

template <int MASK, int COND>
__device__ __forceinline__ float xsum(const float (&v)[32]) {  // half-sum
    float a = 0.f;
#pragma unroll
    for (int j = 0; j < 32; ++j)
        if ((j & COND) == 0) a = fmaf(v[j], v[j ^ MASK], a);
    return a;
}

__device__ __forceinline__ float f4alt(const float* a) {  // sum (-1)^popc(k) a[k]
    const float b0 = a[0] - a[1],   b1 = a[2] - a[3];
    const float b2 = a[4] - a[5],   b3 = a[6] - a[7];
    const float b4 = a[8] - a[9],   b5 = a[10] - a[11];
    const float b6 = a[12] - a[13], b7 = a[14] - a[15];
    const float c0 = b0 - b1, c1 = b2 - b3, c2 = b4 - b5, c3 = b6 - b7;
    return (c0 - c1) - (c2 - c3);
}

extern "C" __global__ void __launch_bounds__(256, 4)
qsim_kernel(const float* __restrict__ base, const float* __restrict__ prm,
            float* __restrict__ out) {
    __shared__ float lds[4][2 * SLABF];  // 8224B per wave slab (2 states)

    const int tid  = threadIdx.x;
    const int wid  = tid >> 6;
    const int lane = tid & 63;
    const int sub  = lane & 31;
    const int st   = lane >> 5;
    const int sid  = blockIdx.x * 8 + wid * 2 + st;
    float* slab  = lds[wid];
    float4* slab4 = reinterpret_cast<float4*>(slab);
    const int stF = st * SLABF;  // float base of this state's half-slab
    const int stU = st * (SLABF / 4);  // float4 base (257)

    const int b0 = sub & 1, b1 = (sub >> 1) & 1, b2 = (sub >> 2) & 1,
              b3 = (sub >> 3) & 1, b4 = (sub >> 4) & 1;

    float c[NQ], s[NQ];
#pragma unroll
    for (int i = 0; i < NQ; ++i) {
        const float h = 0.5f * prm[i];
        s[i] = __sinf(h);
        c[i] = __cosf(h);
    }

    // ---- L0 load (fully coalesced): v[(q<<2)|e] = amp[q<<7 | sub<<2 | e] ----
    // reg bits: j0=y0 j1=y1 j2=y7 j3=y8 j4=y9; lane: sub bits 0..4 = y2..y6
    float v[32];
    const float4* row4 = reinterpret_cast<const float4*>(base + (size_t)sid * DIM);
#pragma unroll
    for (int q = 0; q < 8; ++q) {
        const float4 t = row4[(q << 5) | sub];
        v[4 * q + 0] = t.x; v[4 * q + 1] = t.y;
        v[4 * q + 2] = t.z; v[4 * q + 3] = t.w;
    }

    // ---- Gates at L0: amps (0,1,7,8,9) -> wires (9,8,2,1,0) ----
    gate<1>(v, c[9], s[9]);
    gate<2>(v, c[8], s[8]);
    gate<4>(v, c[2], s[2]);
    gate<8>(v, c[1], s[1]);
    gate<16>(v, c[0], s[0]);

    // ---- RT1: natural-order store, swizzle y ^= ((y>>8)&3)<<3, stagger +4 ----
#pragma unroll
    for (int q = 0; q < 8; ++q) {
        slab4[stU + (q << 5) + (sub ^ ((q >> 1) << 1))] =
            make_float4(v[4 * q], v[4 * q + 1], v[4 * q + 2], v[4 * q + 3]);
    }
    asm volatile("s_waitcnt lgkmcnt(0)" ::: "memory");
    // read -> L1: reg j' = y2..y6; lane: b0=y0 b1=y1 b2=y7 b3=y8 b4=y9
    {
        const int rb = stF + ((sub >> 2) << 7) + (sub & 3);
        const int xj = (sub >> 3) << 1;  // swizzle: XOR sub bits 3,4 into j bits 1,2
#pragma unroll
        for (int p = 0; p < 16; ++p) {
            const int a = rb + (((2 * p) ^ xj) << 2);
            v[2 * p]     = slab[a];
            v[2 * p + 1] = slab[a + 4];
        }
    }

    // ---- Gates at L1: amps (2,3,4,5,6) -> wires (7,6,5,4,3) ----
    gate<1>(v, c[7], s[7]);
    gate<2>(v, c[6], s[6]);
    gate<4>(v, c[5], s[5]);
    gate<8>(v, c[4], s[4]);
    gate<16>(v, c[3], s[3]);

    // ---- X at L1, register-local edges (half-sums) ----
    float xa[NQ], za[NQ];
    xa[6] = xsum<3, 2>(v);    // d12:  flips y2,y3
    xa[5] = xsum<6, 4>(v);    // d24:  flips y3,y4
    xa[4] = xsum<12, 8>(v);   // d48:  flips y4,y5
    xa[3] = xsum<24, 16>(v);  // d96:  flips y5,y6

    // ---- X at L1, cross-lane edges via quad_perm (full sums, halved) ----
    {
        float f8 = 0.f, f7 = 0.f;
#pragma unroll
        for (int j = 0; j < 32; ++j)
            f8 = fmaf(v[j], dpp_mov<0x1B, 0xF>(v[j]), f8);      // xor3: y0,y1
#pragma unroll
        for (int j = 0; j < 32; ++j)
            f7 = fmaf(v[j], dpp_mov<0x4E, 0xF>(v[j ^ 1]), f7);  // xor2 + j^1: y1,y2
        xa[8] = 0.5f * f8;  // w8 (d3)
        xa[7] = 0.5f * f7;  // w7 (d6)
    }

    // ---- Z (all wires) at L1: S-masks over reg bits y2..y6, lane parities ----
    {
        float A1[16], D1[16];
#pragma unroll
        for (int k = 0; k < 16; ++k) {
            const float s0q = v[2 * k] * v[2 * k];
            const float s1q = v[2 * k + 1] * v[2 * k + 1];
            A1[k] = s0q + s1q;
            D1[k] = s0q - s1q;
        }
        const float S31 = f4alt(D1);  // signs over y2..y6
        const float S30 = f4alt(A1);  // signs over y3..y6
        float A2[8];
#pragma unroll
        for (int k = 0; k < 8; ++k) A2[k] = A1[2 * k] + A1[2 * k + 1];
        const float S28 = ((A2[0] - A2[1]) - (A2[2] - A2[3])) -
                          ((A2[4] - A2[5]) - (A2[6] - A2[7]));  // y4,y5,y6
        float A3[4];
#pragma unroll
        for (int k = 0; k < 4; ++k) A3[k] = A2[2 * k] + A2[2 * k + 1];
        const float S24 = (A3[0] - A3[1]) - (A3[2] - A3[3]);    // y5,y6
        const float S16 = (A3[0] + A3[1]) - (A3[2] + A3[3]);    // y6
        const float S0  = (A3[0] + A3[1]) + (A3[2] + A3[3]);

        // lane parities: b2,b3,b4 = y7,y8,y9; b0,b1 = y0,y1
        const float sgA = (__popc(sub >> 2) & 1) ? -1.f : 1.f;  // y7^y8^y9
        const float sg9 = b4 ? -1.f : 1.f;                      // y9
        const float sg89 = (__popc(sub >> 3) & 1) ? -1.f : 1.f; // y8^y9
        const float sg1A = (__popc(sub >> 1) & 1) ? -1.f : 1.f; // y1^y7^y8^y9
        const float sg0A = (__popc(sub) & 1) ? -1.f : 1.f;      // y0^..^y9 lane part

        za[0] = sg9 * S0;    // b=9
        za[1] = sg89 * S0;   // b=8
        za[2] = sgA * S0;    // b=7
        za[3] = sgA * S16;   // b=6
        za[4] = sgA * S24;   // b=5
        za[5] = sgA * S28;   // b=4
        za[6] = sgA * S30;   // b=3
        za[7] = sgA * S31;   // b=2
        za[8] = sg1A * S31;  // b=1
        za[9] = sg0A * S31;  // b=0
        xa[0] = S0;          // stash S0 for n2 (overwritten below after reduce? no:
        // xa[0] is assigned at L3 later; use a dedicated variable instead.
    }
    float S0v;
    {
        // recover S0 cheaply: za[2] = sgA*S0 -> S0 = sgA*za[2]
        const float sgA = (__popc(sub >> 2) & 1) ? -1.f : 1.f;
        S0v = sgA * za[2];
    }

    // ---- RT2: L1 -> L3.  LDS map m(y): uh = [y0, y1, y7^y4, y4, y5, y6, y8, y9],
    //      elements (y2,y3); stagger +4 floats for st=1. ----
#pragma unroll
    for (int p = 0; p < 8; ++p) {
        const int uh = b0 | (b1 << 1) | ((b2 ^ (p & 1)) << 2) | (p << 3) |
                       (b3 << 6) | (b4 << 7);
        slab4[stU + uh] = make_float4(v[4 * p], v[4 * p + 1], v[4 * p + 2], v[4 * p + 3]);
    }
    asm volatile("s_waitcnt lgkmcnt(0)" ::: "memory");
    // read -> L3: reg j: j0=y0 j1=y6 j2=y7 j3=y8 j4=y9; lane: b0..b4 = y1..y5
    {
        const int low = b1 | (b2 << 1);  // (y2,y3)
#pragma unroll
        for (int p = 0; p < 16; ++p) {
            const int j  = 2 * p;
            const int j1 = (j >> 1) & 1, j2 = (j >> 2) & 1,
                      j3 = (j >> 3) & 1, j4 = (j >> 4) & 1;
            const int uh = (b0 << 1) | ((j2 ^ b3) << 2) | (b3 << 3) | (b4 << 4) |
                           (j1 << 5) | (j3 << 6) | (j4 << 7);
            const int a = stF + (uh << 2) + low;
            v[j]     = slab[a];
            v[j + 1] = slab[a + 4];
        }
    }

    // ---- X at L3 (regs y0,y6,y7,y8,y9), register-local (half-sums) ----
    xa[9] = xsum<1, 1>(v);    // d1:   flips y0
    xa[2] = xsum<6, 4>(v);    // d192: flips y6,y7
    xa[1] = xsum<12, 8>(v);   // d384: flips y7,y8
    xa[0] = xsum<24, 16>(v);  // d768: flips y8,y9

    // ---- Reduce over the 32 lanes of each state ----
    float n2 = red32(S0v);
#pragma unroll
    for (int w = 0; w < NQ; ++w) {
        xa[w] = red32(xa[w]);
        za[w] = red32(za[w]);
    }

    if (sub == 31) {
        const float inv = 1.0f / n2;
        float* o = out + (size_t)sid * (3 * NQ);
#pragma unroll
        for (int w = 0; w < NQ; ++w) {
            o[3 * w + 0] = 2.0f * xa[w] * inv;
            o[3 * w + 1] = 0.0f;
            o[3 * w + 2] = za[w] * inv;
        }
    }
}

extern "C" void kernel_launch(void* const* d_in, const int* in_sizes, int n_in,
                              void* d_out, int out_size, void* d_ws, size_t ws_size,
                              hipStream_t stream) {
    const float* base = (const float*)d_in[0];
    const float* prm  = (const float*)d_in[1];
    float* out        = (float*)d_out;
    const int nstates = in_sizes[0] / DIM;  // 32768
    const int blocks  = nstates / 8;        // 8 states per 256-thread block
    qsim_kernel<<<dim3(blocks), dim3(256), 0, stream>>>(base, prm, out);
}